// Round 1
// baseline (419.253 us; speedup 1.0000x reference)
//
#include <hip/hip_runtime.h>
#include <math.h>

// Rs_GCN non-local block, restructured:
//   S[b]     = phi[b] @ g[b]^T                  [Ci,Ci]   (split-K over N, atomics)
//   Mt[b]    = S[b] @ Ww^T   (stored [i][o])    [Ci,C]
//   WeffT[b] = (1/N) * Wth^T-contracted: WeffT[p][o] = (1/N) sum_i Wth[i][p]*Mt[b][i][o]
//   b_eff[b][o] = (1/N) sum_i Mt[b][i][o]*bth[i] + bw[o]
//   Wy[b]    = WeffT[b]^T @ v[b] + b_eff        (written to d_out)
//   BN stats over (B,N) per channel, then out = Wy*scale + shift + v  (in place)

#define B_  4
#define C_  512
#define CI_ 256
#define N_  4096

// ---------------- transpose [CI_][C_] -> [C_][CI_], two weights in one launch ---------
__global__ __launch_bounds__(256) void transpose_w(
    const float* __restrict__ W1, const float* __restrict__ W2,
    float* __restrict__ T1, float* __restrict__ T2)
{
    __shared__ float tile[32][33];
    const float* W = blockIdx.z ? W2 : W1;
    float* T = blockIdx.z ? T2 : T1;
    int c0 = blockIdx.x * 32;           // C dim (512): grid.x = 16
    int r0 = blockIdx.y * 32;           // Ci dim (256): grid.y = 8
    int tx = threadIdx.x & 31, ty = threadIdx.x >> 5;   // 32 x 8
#pragma unroll
    for (int j = 0; j < 32; j += 8)
        tile[ty + j][tx] = W[(r0 + ty + j) * C_ + c0 + tx];
    __syncthreads();
#pragma unroll
    for (int j = 0; j < 32; j += 8)
        T[(c0 + ty + j) * CI_ + r0 + tx] = tile[tx][ty + j];
}

// ---------------- proj: out[b][o][n] = bias[o] + sum_c Wt[c][o]*v[b][c][n] ------------
// M=256, N=4096, K=512.  128x128 tile, 256 threads, 8x8 micro-tile.
// grid (32, 2, 8): z = sel*4 + b  (sel 0 -> phi, 1 -> g) => 512 blocks = 2/CU.
__global__ __launch_bounds__(256) void proj_dual(
    const float* __restrict__ v,
    const float* __restrict__ Wt1, const float* __restrict__ bias1, float* __restrict__ out1,
    const float* __restrict__ Wt2, const float* __restrict__ bias2, float* __restrict__ out2)
{
    int z = blockIdx.z;
    int b = z & 3, sel = z >> 2;
    const float* Wt   = sel ? Wt2 : Wt1;
    const float* bias = sel ? bias2 : bias1;
    float* outp = (sel ? out2 : out1) + (long)b * CI_ * N_;
    const float* vb = v + (long)b * C_ * N_;

    int n0 = blockIdx.x * 128;
    int m0 = blockIdx.y * 128;

    __shared__ __align__(16) float As[16][128];
    __shared__ __align__(16) float Bs[16][128];

    int t = threadIdx.x;
    int tx = t & 15, ty = t >> 4;

    float acc[8][8];
#pragma unroll
    for (int r = 0; r < 8; ++r)
#pragma unroll
        for (int c = 0; c < 8; ++c) acc[r][c] = 0.f;

    for (int k0 = 0; k0 < C_; k0 += 16) {
#pragma unroll
        for (int i = 0; i < 2; ++i) {
            int fi = t + i * 256;               // 0..511 float4 slots
            int k = fi >> 5, c4 = (fi & 31) << 2;
            *(float4*)&As[k][c4] = *(const float4*)&Wt[(k0 + k) * CI_ + m0 + c4];
            *(float4*)&Bs[k][c4] = *(const float4*)&vb[(long)(k0 + k) * N_ + n0 + c4];
        }
        __syncthreads();
#pragma unroll
        for (int k = 0; k < 16; ++k) {
            float4 a0 = *(float4*)&As[k][ty * 4];
            float4 a1 = *(float4*)&As[k][ty * 4 + 64];
            float4 b0 = *(float4*)&Bs[k][tx * 4];
            float4 b1 = *(float4*)&Bs[k][tx * 4 + 64];
            float a[8]  = {a0.x, a0.y, a0.z, a0.w, a1.x, a1.y, a1.z, a1.w};
            float bb[8] = {b0.x, b0.y, b0.z, b0.w, b1.x, b1.y, b1.z, b1.w};
#pragma unroll
            for (int r = 0; r < 8; ++r)
#pragma unroll
                for (int c = 0; c < 8; ++c)
                    acc[r][c] += a[r] * bb[c];
        }
        __syncthreads();
    }
#pragma unroll
    for (int r = 0; r < 8; ++r) {
        int m = m0 + ((r < 4) ? (ty * 4 + r) : (64 + ty * 4 + r - 4));
        float bv = bias[m];
        float4 o0 = make_float4(acc[r][0] + bv, acc[r][1] + bv, acc[r][2] + bv, acc[r][3] + bv);
        float4 o1 = make_float4(acc[r][4] + bv, acc[r][5] + bv, acc[r][6] + bv, acc[r][7] + bv);
        *(float4*)&outp[(long)m * N_ + n0 + tx * 4] = o0;
        *(float4*)&outp[(long)m * N_ + n0 + 64 + tx * 4] = o1;
    }
}

// ---------------- Wy: out[b][o][n] = beff[b][o] + sum_p WeffT[b][p][o]*v[b][p][n] -----
// M=512, N=4096, K=512.  Same 128x128 structure. grid (32, 4, 4) = 512 blocks.
__global__ __launch_bounds__(256) void wy_gemm(
    const float* __restrict__ WeffT, const float* __restrict__ beff,
    const float* __restrict__ v, float* __restrict__ out)
{
    int b = blockIdx.z;
    const float* At   = WeffT + (long)b * C_ * C_;
    const float* bias = beff + b * C_;
    const float* vb   = v + (long)b * C_ * N_;
    float* outp       = out + (long)b * C_ * N_;

    int n0 = blockIdx.x * 128;
    int m0 = blockIdx.y * 128;

    __shared__ __align__(16) float As[16][128];
    __shared__ __align__(16) float Bs[16][128];

    int t = threadIdx.x;
    int tx = t & 15, ty = t >> 4;

    float acc[8][8];
#pragma unroll
    for (int r = 0; r < 8; ++r)
#pragma unroll
        for (int c = 0; c < 8; ++c) acc[r][c] = 0.f;

    for (int k0 = 0; k0 < C_; k0 += 16) {
#pragma unroll
        for (int i = 0; i < 2; ++i) {
            int fi = t + i * 256;
            int k = fi >> 5, c4 = (fi & 31) << 2;
            *(float4*)&As[k][c4] = *(const float4*)&At[(k0 + k) * C_ + m0 + c4];
            *(float4*)&Bs[k][c4] = *(const float4*)&vb[(long)(k0 + k) * N_ + n0 + c4];
        }
        __syncthreads();
#pragma unroll
        for (int k = 0; k < 16; ++k) {
            float4 a0 = *(float4*)&As[k][ty * 4];
            float4 a1 = *(float4*)&As[k][ty * 4 + 64];
            float4 b0 = *(float4*)&Bs[k][tx * 4];
            float4 b1 = *(float4*)&Bs[k][tx * 4 + 64];
            float a[8]  = {a0.x, a0.y, a0.z, a0.w, a1.x, a1.y, a1.z, a1.w};
            float bb[8] = {b0.x, b0.y, b0.z, b0.w, b1.x, b1.y, b1.z, b1.w};
#pragma unroll
            for (int r = 0; r < 8; ++r)
#pragma unroll
                for (int c = 0; c < 8; ++c)
                    acc[r][c] += a[r] * bb[c];
        }
        __syncthreads();
    }
#pragma unroll
    for (int r = 0; r < 8; ++r) {
        int m = m0 + ((r < 4) ? (ty * 4 + r) : (64 + ty * 4 + r - 4));
        float bv = bias[m];
        float4 o0 = make_float4(acc[r][0] + bv, acc[r][1] + bv, acc[r][2] + bv, acc[r][3] + bv);
        float4 o1 = make_float4(acc[r][4] + bv, acc[r][5] + bv, acc[r][6] + bv, acc[r][7] + bv);
        *(float4*)&outp[(long)m * N_ + n0 + tx * 4] = o0;
        *(float4*)&outp[(long)m * N_ + n0 + 64 + tx * 4] = o1;
    }
}

// ---------------- NT gemm: C[i][j] (+)= sum_k A[i][k]*B[j][k]  (reduction contiguous) --
// 64x64 tile, 4x4 micro. Optional split-K with atomic accumulate.
__global__ __launch_bounds__(256) void gemm_nt(
    const float* __restrict__ A, long sA, int lda,
    const float* __restrict__ Bm, long sB, int ldb,
    float* __restrict__ Cm, long sC, int ldc,
    int kChunk, int nChunks, int accumulate)
{
    int z = blockIdx.z;
    int b = z / nChunks, ch = z - b * nChunks;
    const float* Ab = A + (long)b * sA;
    const float* Bb = Bm + (long)b * sB;
    float* Cb = Cm + (long)b * sC;
    int k0 = ch * kChunk;
    int i0 = blockIdx.y * 64, j0 = blockIdx.x * 64;

    __shared__ __align__(16) float As[16][64];
    __shared__ __align__(16) float Bs[16][64];

    int t = threadIdx.x, tx = t & 15, ty = t >> 4;
    int lr = t >> 2, lk = (t & 3) << 2;    // 64 rows x 4 float4-of-k per tile

    float acc[4][4];
#pragma unroll
    for (int r = 0; r < 4; ++r)
#pragma unroll
        for (int c = 0; c < 4; ++c) acc[r][c] = 0.f;

    for (int kt = 0; kt < kChunk; kt += 16) {
        float4 va = *(const float4*)&Ab[(long)(i0 + lr) * lda + k0 + kt + lk];
        float4 vb = *(const float4*)&Bb[(long)(j0 + lr) * ldb + k0 + kt + lk];
        As[lk + 0][lr] = va.x; As[lk + 1][lr] = va.y; As[lk + 2][lr] = va.z; As[lk + 3][lr] = va.w;
        Bs[lk + 0][lr] = vb.x; Bs[lk + 1][lr] = vb.y; Bs[lk + 2][lr] = vb.z; Bs[lk + 3][lr] = vb.w;
        __syncthreads();
#pragma unroll
        for (int k = 0; k < 16; ++k) {
            float4 a4 = *(float4*)&As[k][ty * 4];
            float4 b4 = *(float4*)&Bs[k][tx * 4];
            float a[4]  = {a4.x, a4.y, a4.z, a4.w};
            float bb[4] = {b4.x, b4.y, b4.z, b4.w};
#pragma unroll
            for (int r = 0; r < 4; ++r)
#pragma unroll
                for (int c = 0; c < 4; ++c)
                    acc[r][c] += a[r] * bb[c];
        }
        __syncthreads();
    }
    if (accumulate) {
#pragma unroll
        for (int r = 0; r < 4; ++r)
#pragma unroll
            for (int c = 0; c < 4; ++c)
                atomicAdd(&Cb[(long)(i0 + ty * 4 + r) * ldc + j0 + tx * 4 + c], acc[r][c]);
    } else {
#pragma unroll
        for (int r = 0; r < 4; ++r) {
            float4 o0 = make_float4(acc[r][0], acc[r][1], acc[r][2], acc[r][3]);
            *(float4*)&Cb[(long)(i0 + ty * 4 + r) * ldc + j0 + tx * 4] = o0;
        }
    }
}

// ---------------- generic AtB 64x64 (used for WeffT) ----------------------------------
// C[m][n] = scale * sum_k At[k][m]*B[k][n]
__global__ __launch_bounds__(256) void gemm_atb64(
    const float* __restrict__ At, long sAt,
    const float* __restrict__ Bm, long sB,
    float* __restrict__ Cm, long sC,
    int M, int N, int K, float scale)
{
    int b = blockIdx.z;
    const float* Atb = At + (long)b * sAt;
    const float* Bb  = Bm + (long)b * sB;
    float* Cb = Cm + (long)b * sC;
    int n0 = blockIdx.x * 64, m0 = blockIdx.y * 64;

    __shared__ __align__(16) float As[16][64];
    __shared__ __align__(16) float Bs[16][64];

    int t = threadIdx.x, tx = t & 15, ty = t >> 4;
    int lk = t >> 4, lc = (t & 15) << 2;

    float acc[4][4];
#pragma unroll
    for (int r = 0; r < 4; ++r)
#pragma unroll
        for (int c = 0; c < 4; ++c) acc[r][c] = 0.f;

    for (int k0 = 0; k0 < K; k0 += 16) {
        *(float4*)&As[lk][lc] = *(const float4*)&Atb[(long)(k0 + lk) * M + m0 + lc];
        *(float4*)&Bs[lk][lc] = *(const float4*)&Bb[(long)(k0 + lk) * N + n0 + lc];
        __syncthreads();
#pragma unroll
        for (int k = 0; k < 16; ++k) {
            float4 a4 = *(float4*)&As[k][ty * 4];
            float4 b4 = *(float4*)&Bs[k][tx * 4];
            float a[4]  = {a4.x, a4.y, a4.z, a4.w};
            float bb[4] = {b4.x, b4.y, b4.z, b4.w};
#pragma unroll
            for (int r = 0; r < 4; ++r)
#pragma unroll
                for (int c = 0; c < 4; ++c)
                    acc[r][c] += a[r] * bb[c];
        }
        __syncthreads();
    }
#pragma unroll
    for (int r = 0; r < 4; ++r) {
        float4 o0 = make_float4(acc[r][0] * scale, acc[r][1] * scale,
                                acc[r][2] * scale, acc[r][3] * scale);
        *(float4*)&Cb[(long)(m0 + ty * 4 + r) * N + n0 + tx * 4] = o0;
    }
}

// ---------------- b_eff[b][o] = (1/N) sum_i Mt[b][i][o]*bth[i] + bw[o] ----------------
__global__ __launch_bounds__(512) void beff_kernel(
    const float* __restrict__ Mt, const float* __restrict__ bth,
    const float* __restrict__ bw, float* __restrict__ beff)
{
    int b = blockIdx.x;
    int o = threadIdx.x;
    float s = 0.f;
    for (int i = 0; i < CI_; ++i)
        s += Mt[((long)b * CI_ + i) * C_ + o] * bth[i];
    beff[b * C_ + o] = s * (1.0f / (float)N_) + bw[o];
}

// ---------------- BN stats: per-channel mean/var over (B,N) ---------------------------
__global__ __launch_bounds__(256) void bn_stats(
    const float* __restrict__ Wy, const float* __restrict__ gamma,
    const float* __restrict__ beta, float* __restrict__ scale, float* __restrict__ shift)
{
    int o = blockIdx.x;
    float s = 0.f, ss = 0.f;
    for (int b = 0; b < B_; ++b) {
        const float4* p = (const float4*)(Wy + ((long)b * C_ + o) * N_);
        for (int i = threadIdx.x; i < N_ / 4; i += 256) {
            float4 w = p[i];
            s  += w.x + w.y + w.z + w.w;
            ss += w.x * w.x + w.y * w.y + w.z * w.z + w.w * w.w;
        }
    }
#pragma unroll
    for (int off = 32; off > 0; off >>= 1) {
        s  += __shfl_down(s, off);
        ss += __shfl_down(ss, off);
    }
    __shared__ float rs[4], rss[4];
    int wid = threadIdx.x >> 6;
    if ((threadIdx.x & 63) == 0) { rs[wid] = s; rss[wid] = ss; }
    __syncthreads();
    if (threadIdx.x == 0) {
        float st  = rs[0] + rs[1] + rs[2] + rs[3];
        float sst = rss[0] + rss[1] + rss[2] + rss[3];
        const float inv_cnt = 1.0f / (float)(B_ * N_);
        float mean = st * inv_cnt;
        float var  = sst * inv_cnt - mean * mean;
        float inv  = 1.0f / sqrtf(var + 1e-5f);
        float sc = inv * gamma[o];
        scale[o] = sc;
        shift[o] = beta[o] - mean * sc;
    }
}

// ---------------- out = out*scale[o] + shift[o] + v  (in place, float4) ---------------
__global__ __launch_bounds__(256) void bn_apply(
    float* __restrict__ out, const float* __restrict__ v,
    const float* __restrict__ scale, const float* __restrict__ shift)
{
    long i = (long)blockIdx.x * 256 + threadIdx.x;     // float4 index
    int o = (int)((i >> 10) & (C_ - 1));               // 1024 float4 per (b,o) row
    float4 w  = ((const float4*)out)[i];
    float4 vv = ((const float4*)v)[i];
    float sc = scale[o], sh = shift[o];
    w.x = w.x * sc + sh + vv.x;
    w.y = w.y * sc + sh + vv.y;
    w.z = w.z * sc + sh + vv.z;
    w.w = w.w * sc + sh + vv.w;
    ((float4*)out)[i] = w;
}

extern "C" void kernel_launch(void* const* d_in, const int* in_sizes, int n_in,
                              void* d_out, int out_size, void* d_ws, size_t ws_size,
                              hipStream_t stream)
{
    const float* v    = (const float*)d_in[0];
    const float* Wg   = (const float*)d_in[1];
    const float* bg   = (const float*)d_in[2];
    const float* Wth  = (const float*)d_in[3];
    const float* bth  = (const float*)d_in[4];
    const float* Wph  = (const float*)d_in[5];
    const float* bph  = (const float*)d_in[6];
    const float* Ww   = (const float*)d_in[7];
    const float* bw   = (const float*)d_in[8];
    const float* gamma = (const float*)d_in[9];
    const float* beta  = (const float*)d_in[10];
    float* out = (float*)d_out;
    float* ws  = (float*)d_ws;

    // workspace layout (floats), all offsets 16B-aligned; total ~40 MB
    float* S_    = ws + 0;          //  262144  [B][256][256]
    float* Mt_   = ws + 262144;     //  524288  [B][256][512]  (Mt[i][o] = M[o][i])
    float* WtPh  = ws + 786432;     //  131072  [512][256]
    float* WtG   = ws + 917504;     //  131072
    float* beff  = ws + 1048576;    //    2048  [B][512]
    float* scale = ws + 1050624;    //     512
    float* shift = ws + 1051136;    //     512
    float* phi   = ws + 1052672;    // 4194304  [B][256][4096]
    float* g     = ws + 5246976;    // 4194304
    float* WeffT = ws + 9441280;    // 1048576  [B][512][512]  (WeffT[p][o])

    // S is accumulated with atomics -> zero it (ws re-poisoned to 0xAA each call)
    hipMemsetAsync(S_, 0, 262144 * sizeof(float), stream);

    // W transposes for coalesced GEMM-A loads
    transpose_w<<<dim3(16, 8, 2), 256, 0, stream>>>(Wph, Wg, WtPh, WtG);

    // phi = Wph@v + bph ; g = Wg@v + bg   (one launch, 512 blocks)
    proj_dual<<<dim3(32, 2, 8), 256, 0, stream>>>(v, WtPh, bph, phi, WtG, bg, g);

    // S[b][i][j] = sum_m phi[b][i][m] * g[b][j][m]   (split-K x8, atomic)
    gemm_nt<<<dim3(4, 4, 32), 256, 0, stream>>>(
        phi, (long)CI_ * N_, N_, g, (long)CI_ * N_, N_,
        S_, (long)CI_ * CI_, CI_, 512, 8, 1);

    // Mt[b][i][o] = sum_c S[b][i][c] * Ww[o][c]
    gemm_nt<<<dim3(8, 4, 4), 256, 0, stream>>>(
        S_, (long)CI_ * CI_, CI_, Ww, 0, CI_,
        Mt_, (long)CI_ * C_, C_, 256, 1, 0);

    // b_eff
    beff_kernel<<<dim3(4), 512, 0, stream>>>(Mt_, bth, bw, beff);

    // WeffT[b][p][o] = (1/N) sum_i Wth[i][p] * Mt[b][i][o]
    gemm_atb64<<<dim3(8, 8, 4), 256, 0, stream>>>(
        Wth, 0, Mt_, (long)CI_ * C_, WeffT, (long)C_ * C_,
        C_, C_, CI_, 1.0f / (float)N_);

    // Wy = WeffT^T @ v + b_eff  -> d_out
    wy_gemm<<<dim3(32, 4, 4), 256, 0, stream>>>(WeffT, beff, v, out);

    // BN stats then fused apply + residual
    bn_stats<<<dim3(512), 256, 0, stream>>>(out, gamma, beta, scale, shift);
    bn_apply<<<dim3(8192), 256, 0, stream>>>(out, v, scale, shift);
}

// Round 2
// 366.369 us; speedup vs baseline: 1.1443x; 1.1443x over previous
//
#include <hip/hip_runtime.h>
#include <math.h>

// Rs_GCN, round 2: bf16 hi/lo (3-term) MFMA for the two heavy GEMMs.
//   G[b]   = V V^T  (MFMA, split-K=8, partials overlay vth buffer)
//   S'     = Wg G Wph^T + u1 bph^T + bg u2^T + N bg bph^T   (fp32 chain)
//   Weff   = (1/N) Ww S' Wth ; beff = (1/N) Ww S' bth + bw
//   Wy     = Weff v + beff   (MFMA, stats fused)   -> BN -> +v

#define B_  4
#define C_  512
#define CI_ 256
#define N_  4096

typedef __attribute__((ext_vector_type(8))) short bf16x8;
typedef __attribute__((ext_vector_type(4))) float f32x4;

// ---- ws float offsets -------------------------------------------------------
#define G_OFF     0L          // 1,048,576
#define P1_OFF    1048576L    //   524,288
#define SP_OFF    1572864L    //   262,144
#define P2_OFF    1835008L    //   524,288
#define WEFF_OFF  2359296L    // 1,048,576
#define WWT_OFF   3407872L    //   131,072
#define WTHT_OFF  3538944L    //   131,072
#define MISC_OFF  3670016L    //     8,192
#define R_OFF     (MISC_OFF + 0)
#define SUM_OFF   (MISC_OFF + 2048)
#define SSQ_OFF   (MISC_OFF + 2560)
#define U1_OFF    (MISC_OFF + 3072)
#define U2_OFF    (MISC_OFF + 4096)
#define SC_OFF    (MISC_OFF + 5120)
#define SH_OFF    (MISC_OFF + 5632)
#define BE_OFF    (MISC_OFF + 6144)
#define VH_OFF    3678208L    // ushort[8,388,608] = 4,194,304 float slots
#define VL_OFF    7872512L
#define VTH_OFF   12066816L   // gram partials (8.39M floats) overlay VTH+VTL
#define VTL_OFF   16261120L
#define WEH_OFF   20455424L   //   524,288 slots (ushort 1,048,576)
#define WEL_OFF   20979712L
// total 21,504,000 floats ~= 86 MB

// ---- helpers ----------------------------------------------------------------
__device__ __forceinline__ unsigned short f2bf(float f) {
    union { float f; unsigned int u; } a; a.f = f;
    unsigned int u = a.u;
    u += 0x7fffu + ((u >> 16) & 1u);      // round-to-nearest-even
    return (unsigned short)(u >> 16);
}
__device__ __forceinline__ float bf2f(unsigned short s) {
    union { unsigned int u; float f; } a; a.u = ((unsigned int)s) << 16; return a.f;
}
__device__ __forceinline__ void gload_lds16(const char* g, char* l) {
    __builtin_amdgcn_global_load_lds(
        (const __attribute__((address_space(1))) unsigned int*)g,
        (__attribute__((address_space(3))) unsigned int*)l, 16, 0, 0);
}

// ---- cast1: v -> vh, vl ; rowsum r (atomics) --------------------------------
__global__ __launch_bounds__(256) void cast1(
    const float* __restrict__ v, unsigned short* __restrict__ vh,
    unsigned short* __restrict__ vl, float* __restrict__ r)
{
    long idx = (long)blockIdx.x * 256 + threadIdx.x;   // float4 index, 2,097,152
    float4 f = ((const float4*)v)[idx];
    ushort4 h, l;
    h.x = f2bf(f.x); l.x = f2bf(f.x - bf2f(h.x));
    h.y = f2bf(f.y); l.y = f2bf(f.y - bf2f(h.y));
    h.z = f2bf(f.z); l.z = f2bf(f.z - bf2f(h.z));
    h.w = f2bf(f.w); l.w = f2bf(f.w - bf2f(h.w));
    ((ushort4*)vh)[idx] = h;
    ((ushort4*)vl)[idx] = l;
    float s = f.x + f.y + f.z + f.w;
    s += __shfl_xor(s, 1);  s += __shfl_xor(s, 2);  s += __shfl_xor(s, 4);
    s += __shfl_xor(s, 8);  s += __shfl_xor(s, 16); s += __shfl_xor(s, 32);
    if ((threadIdx.x & 63) == 0) atomicAdd(&r[idx >> 10], s);   // row = idx*4/4096
}

// ---- cast2: v -> vth, vtl  ([B][N][C] transposed, hi/lo packed 2/uint) ------
__global__ __launch_bounds__(256) void cast2_transpose(
    const float* __restrict__ v, unsigned int* __restrict__ vth,
    unsigned int* __restrict__ vtl)
{
    __shared__ float tile[32][33];
    const int b = blockIdx.z;
    const int n0 = blockIdx.x * 32, c0 = blockIdx.y * 32;
    const int t = threadIdx.x, tx = t & 31, ty = t >> 5;
#pragma unroll
    for (int j = 0; j < 4; ++j)
        tile[ty + 8 * j][tx] = v[((long)b * C_ + c0 + ty + 8 * j) * N_ + n0 + tx];
    __syncthreads();
#pragma unroll
    for (int p = 0; p < 2; ++p) {
        int nl = p * 16 + (t >> 4);
        int cl = (t & 15) * 2;
        float f0 = tile[cl][nl], f1 = tile[cl + 1][nl];
        unsigned short h0 = f2bf(f0), h1 = f2bf(f1);
        unsigned short l0 = f2bf(f0 - bf2f(h0)), l1 = f2bf(f1 - bf2f(h1));
        long e = ((long)b * N_ + n0 + nl) * C_ + c0 + cl;
        vth[e >> 1] = (unsigned int)h0 | ((unsigned int)h1 << 16);
        vtl[e >> 1] = (unsigned int)l0 | ((unsigned int)l1 << 16);
    }
}

// ---- castW: Weff -> hi/lo bf16 ----------------------------------------------
__global__ __launch_bounds__(256) void castW(
    const float* __restrict__ Weff, unsigned short* __restrict__ weh,
    unsigned short* __restrict__ wel)
{
    long idx = (long)blockIdx.x * 256 + threadIdx.x;   // float4, 262,144
    float4 f = ((const float4*)Weff)[idx];
    ushort4 h, l;
    h.x = f2bf(f.x); l.x = f2bf(f.x - bf2f(h.x));
    h.y = f2bf(f.y); l.y = f2bf(f.y - bf2f(h.y));
    h.z = f2bf(f.z); l.z = f2bf(f.z - bf2f(h.z));
    h.w = f2bf(f.w); l.w = f2bf(f.w - bf2f(h.w));
    ((ushort4*)weh)[idx] = h;
    ((ushort4*)wel)[idx] = l;
}

// ---- gram: Gp[z] = Vb[m-tile] . Vb[n-tile]^T over k-chunk (hi/lo 3-term) ----
// grid (4,4,32) z = b*8+ch, 256 thr = 4 waves, tile 128x128, BK=64, K=512/chunk
__global__ __launch_bounds__(256, 2) void gram_mfma(
    const unsigned short* __restrict__ vh, const unsigned short* __restrict__ vl,
    float* __restrict__ Gp)
{
    __shared__ char smem[65536];    // Ah | Al | Bh | Bl, 16KB each, rows of 128B
    const int t = threadIdx.x, lane = t & 63, w = t >> 6;
    const int z = blockIdx.z, b = z >> 3, ch = z & 7;
    const long m0 = blockIdx.y * 128, n0 = blockIdx.x * 128;
    const long k0b = (long)ch * 1024;                  // 512 elem * 2B

    const unsigned short* src = (w & 1) ? vl : vh;
    const long row0 = (w < 2) ? m0 : n0;
    const char* g = (const char*)(src + ((long)b * C_ + row0) * N_) + k0b;
    const long stride = (long)N_ * 2;                  // 8192 B
    const char* gs = g + (long)(lane >> 3) * stride + (((lane & 7) ^ (lane >> 3)) << 4);
    char* lbase = smem + w * 16384;

    const int wr = w >> 1, wc = w & 1;
    const int l15 = lane & 15, hi4 = lane >> 4;
    const int swz = (l15 & 7) << 4;
    const int arow = (wr * 64 + l15) * 128;
    const int brow = (wc * 64 + l15) * 128;
    const char* Ah = smem;          const char* Al = smem + 16384;
    const char* Bh = smem + 32768;  const char* Bl = smem + 49152;

    f32x4 acc[4][4];
#pragma unroll
    for (int mi = 0; mi < 4; ++mi)
#pragma unroll
        for (int nj = 0; nj < 4; ++nj) acc[mi][nj] = (f32x4){0.f, 0.f, 0.f, 0.f};

    for (int s = 0; s < 8; ++s) {
#pragma unroll
        for (int i = 0; i < 16; ++i)
            gload_lds16(gs + (long)i * 8 * stride + s * 128, lbase + i * 1024);
        __syncthreads();   // emits waitcnt vmcnt(0) before barrier
#pragma unroll
        for (int kk = 0; kk < 2; ++kk) {
            const int off = (kk * 64 + hi4 * 16) ^ swz;
            bf16x8 ah[4], al[4], bh[4], bl[4];
#pragma unroll
            for (int mi = 0; mi < 4; ++mi) {
                ah[mi] = *(const bf16x8*)(Ah + arow + mi * 2048 + off);
                al[mi] = *(const bf16x8*)(Al + arow + mi * 2048 + off);
            }
#pragma unroll
            for (int nj = 0; nj < 4; ++nj) {
                bh[nj] = *(const bf16x8*)(Bh + brow + nj * 2048 + off);
                bl[nj] = *(const bf16x8*)(Bl + brow + nj * 2048 + off);
            }
#pragma unroll
            for (int mi = 0; mi < 4; ++mi)
#pragma unroll
                for (int nj = 0; nj < 4; ++nj) {
                    acc[mi][nj] = __builtin_amdgcn_mfma_f32_16x16x32_bf16(ah[mi], bh[nj], acc[mi][nj], 0, 0, 0);
                    acc[mi][nj] = __builtin_amdgcn_mfma_f32_16x16x32_bf16(ah[mi], bl[nj], acc[mi][nj], 0, 0, 0);
                    acc[mi][nj] = __builtin_amdgcn_mfma_f32_16x16x32_bf16(al[mi], bh[nj], acc[mi][nj], 0, 0, 0);
                }
        }
        __syncthreads();
    }
    float* gp = Gp + (long)z * (C_ * C_);
#pragma unroll
    for (int mi = 0; mi < 4; ++mi)
#pragma unroll
        for (int nj = 0; nj < 4; ++nj)
#pragma unroll
            for (int rr = 0; rr < 4; ++rr) {
                long row = m0 + wr * 64 + mi * 16 + hi4 * 4 + rr;
                long col = n0 + wc * 64 + nj * 16 + l15;
                gp[row * C_ + col] = acc[mi][nj][rr];
            }
}

// ---- reduce gram partials -> G ----------------------------------------------
__global__ __launch_bounds__(256) void reduce_g(
    const float* __restrict__ Gp, float* __restrict__ G)
{
    long e4 = (long)blockIdx.x * 256 + threadIdx.x;    // float4 idx, 262,144
    long b = e4 >> 16;
    float4 s = make_float4(0.f, 0.f, 0.f, 0.f);
    for (int ch = 0; ch < 8; ++ch) {
        float4 p = ((const float4*)Gp)[(b * 8 + ch) * 65536 + (e4 & 65535)];
        s.x += p.x; s.y += p.y; s.z += p.z; s.w += p.w;
    }
    ((float4*)G)[e4] = s;
}

// ---- wy: out[b][o][n] = sum_p Weff[o][p] v[p][n] + beff ; fused BN stats ----
// grid (32,4,4), 256 thr, tile 128x128, BK=64, K=512
__global__ __launch_bounds__(256, 2) void wy_mfma(
    const unsigned short* __restrict__ weh, const unsigned short* __restrict__ wel,
    const unsigned short* __restrict__ vth, const unsigned short* __restrict__ vtl,
    const float* __restrict__ beff, float* __restrict__ out,
    float* __restrict__ sums, float* __restrict__ ssqs)
{
    __shared__ char smem[65536];
    const int t = threadIdx.x, lane = t & 63, w = t >> 6;
    const int b = blockIdx.z;
    const long m0 = blockIdx.y * 128;   // o
    const long n0 = blockIdx.x * 128;   // n

    const char* g;
    if (w < 2) g = (const char*)(((w & 1) ? wel : weh) + ((long)b * C_ + m0) * C_);
    else       g = (const char*)(((w & 1) ? vtl : vth) + ((long)b * N_ + n0) * C_);
    const long stride = (long)C_ * 2;   // 1024 B
    const char* gs = g + (long)(lane >> 3) * stride + (((lane & 7) ^ (lane >> 3)) << 4);
    char* lbase = smem + w * 16384;

    const int wr = w >> 1, wc = w & 1;
    const int l15 = lane & 15, hi4 = lane >> 4;
    const int swz = (l15 & 7) << 4;
    const int arow = (wr * 64 + l15) * 128;
    const int brow = (wc * 64 + l15) * 128;
    const char* Ah = smem;          const char* Al = smem + 16384;
    const char* Bh = smem + 32768;  const char* Bl = smem + 49152;

    f32x4 acc[4][4];
#pragma unroll
    for (int mi = 0; mi < 4; ++mi)
#pragma unroll
        for (int nj = 0; nj < 4; ++nj) acc[mi][nj] = (f32x4){0.f, 0.f, 0.f, 0.f};

    for (int s = 0; s < 8; ++s) {
#pragma unroll
        for (int i = 0; i < 16; ++i)
            gload_lds16(gs + (long)i * 8 * stride + s * 128, lbase + i * 1024);
        __syncthreads();
#pragma unroll
        for (int kk = 0; kk < 2; ++kk) {
            const int off = (kk * 64 + hi4 * 16) ^ swz;
            bf16x8 ah[4], al[4], bh[4], bl[4];
#pragma unroll
            for (int mi = 0; mi < 4; ++mi) {
                ah[mi] = *(const bf16x8*)(Ah + arow + mi * 2048 + off);
                al[mi] = *(const bf16x8*)(Al + arow + mi * 2048 + off);
            }
#pragma unroll
            for (int nj = 0; nj < 4; ++nj) {
                bh[nj] = *(const bf16x8*)(Bh + brow + nj * 2048 + off);
                bl[nj] = *(const bf16x8*)(Bl + brow + nj * 2048 + off);
            }
#pragma unroll
            for (int mi = 0; mi < 4; ++mi)
#pragma unroll
                for (int nj = 0; nj < 4; ++nj) {
                    acc[mi][nj] = __builtin_amdgcn_mfma_f32_16x16x32_bf16(ah[mi], bh[nj], acc[mi][nj], 0, 0, 0);
                    acc[mi][nj] = __builtin_amdgcn_mfma_f32_16x16x32_bf16(ah[mi], bl[nj], acc[mi][nj], 0, 0, 0);
                    acc[mi][nj] = __builtin_amdgcn_mfma_f32_16x16x32_bf16(al[mi], bh[nj], acc[mi][nj], 0, 0, 0);
                }
        }
        __syncthreads();
    }

    // epilogue: bias, store, fused BN partial stats
    float sm[4][4], sq[4][4];
#pragma unroll
    for (int mi = 0; mi < 4; ++mi)
#pragma unroll
        for (int rr = 0; rr < 4; ++rr) { sm[mi][rr] = 0.f; sq[mi][rr] = 0.f; }

#pragma unroll
    for (int mi = 0; mi < 4; ++mi) {
#pragma unroll
        for (int rr = 0; rr < 4; ++rr) {
            long o = m0 + wr * 64 + mi * 16 + hi4 * 4 + rr;
            float bv = beff[b * C_ + o];
#pragma unroll
            for (int nj = 0; nj < 4; ++nj) {
                long n = n0 + wc * 64 + nj * 16 + l15;
                float val = acc[mi][nj][rr] + bv;
                out[((long)b * C_ + o) * N_ + n] = val;
                sm[mi][rr] += val;
                sq[mi][rr] += val * val;
            }
        }
    }
#pragma unroll
    for (int mi = 0; mi < 4; ++mi)
#pragma unroll
        for (int rr = 0; rr < 4; ++rr) {
            float s1 = sm[mi][rr], s2 = sq[mi][rr];
            s1 += __shfl_xor(s1, 1); s2 += __shfl_xor(s2, 1);
            s1 += __shfl_xor(s1, 2); s2 += __shfl_xor(s2, 2);
            s1 += __shfl_xor(s1, 4); s2 += __shfl_xor(s2, 4);
            s1 += __shfl_xor(s1, 8); s2 += __shfl_xor(s2, 8);
            if (l15 == 0) {
                long o = m0 + wr * 64 + mi * 16 + hi4 * 4 + rr;
                atomicAdd(&sums[o], s1);
                atomicAdd(&ssqs[o], s2);
            }
        }
}

// ---- generic fp32 NT gemm: C[i][j] = scale * sum_k A[i][k]B[j][k] -----------
__global__ __launch_bounds__(256) void gemm_nt(
    const float* __restrict__ A, long sA, int lda,
    const float* __restrict__ Bm, long sB, int ldb,
    float* __restrict__ Cm, long sC, int ldc, int K, float scale)
{
    int b = blockIdx.z;
    const float* Ab = A + (long)b * sA;
    const float* Bb = Bm + (long)b * sB;
    float* Cb = Cm + (long)b * sC;
    int i0 = blockIdx.y * 64, j0 = blockIdx.x * 64;

    __shared__ __align__(16) float As[16][64];
    __shared__ __align__(16) float Bs[16][64];

    int t = threadIdx.x, tx = t & 15, ty = t >> 4;
    int lr = t >> 2, lk = (t & 3) << 2;

    float acc[4][4];
#pragma unroll
    for (int r = 0; r < 4; ++r)
#pragma unroll
        for (int c = 0; c < 4; ++c) acc[r][c] = 0.f;

    for (int kt = 0; kt < K; kt += 16) {
        float4 va = *(const float4*)&Ab[(long)(i0 + lr) * lda + kt + lk];
        float4 vb = *(const float4*)&Bb[(long)(j0 + lr) * ldb + kt + lk];
        As[lk + 0][lr] = va.x; As[lk + 1][lr] = va.y; As[lk + 2][lr] = va.z; As[lk + 3][lr] = va.w;
        Bs[lk + 0][lr] = vb.x; Bs[lk + 1][lr] = vb.y; Bs[lk + 2][lr] = vb.z; Bs[lk + 3][lr] = vb.w;
        __syncthreads();
#pragma unroll
        for (int k = 0; k < 16; ++k) {
            float4 a4 = *(float4*)&As[k][ty * 4];
            float4 b4 = *(float4*)&Bs[k][tx * 4];
            float a[4]  = {a4.x, a4.y, a4.z, a4.w};
            float bb[4] = {b4.x, b4.y, b4.z, b4.w};
#pragma unroll
            for (int r = 0; r < 4; ++r)
#pragma unroll
                for (int c = 0; c < 4; ++c)
                    acc[r][c] += a[r] * bb[c];
        }
        __syncthreads();
    }
#pragma unroll
    for (int r = 0; r < 4; ++r) {
        float4 o0 = make_float4(acc[r][0] * scale, acc[r][1] * scale,
                                acc[r][2] * scale, acc[r][3] * scale);
        *(float4*)&Cb[(long)(i0 + ty * 4 + r) * ldc + j0 + tx * 4] = o0;
    }
}

// ---- C[m][n] = scale * sum_k At[k][m]*B[k][n] -------------------------------
__global__ __launch_bounds__(256) void gemm_atb64(
    const float* __restrict__ At, long sAt,
    const float* __restrict__ Bm, long sB,
    float* __restrict__ Cm, long sC,
    int M, int N, int K, float scale)
{
    int b = blockIdx.z;
    const float* Atb = At + (long)b * sAt;
    const float* Bb  = Bm + (long)b * sB;
    float* Cb = Cm + (long)b * sC;
    int n0 = blockIdx.x * 64, m0 = blockIdx.y * 64;

    __shared__ __align__(16) float As[16][64];
    __shared__ __align__(16) float Bs[16][64];

    int t = threadIdx.x, tx = t & 15, ty = t >> 4;
    int lk = t >> 4, lc = (t & 15) << 2;

    float acc[4][4];
#pragma unroll
    for (int r = 0; r < 4; ++r)
#pragma unroll
        for (int c = 0; c < 4; ++c) acc[r][c] = 0.f;

    for (int k0 = 0; k0 < K; k0 += 16) {
        *(float4*)&As[lk][lc] = *(const float4*)&Atb[(long)(k0 + lk) * M + m0 + lc];
        *(float4*)&Bs[lk][lc] = *(const float4*)&Bb[(long)(k0 + lk) * N + n0 + lc];
        __syncthreads();
#pragma unroll
        for (int k = 0; k < 16; ++k) {
            float4 a4 = *(float4*)&As[k][ty * 4];
            float4 b4 = *(float4*)&Bs[k][tx * 4];
            float a[4]  = {a4.x, a4.y, a4.z, a4.w};
            float bb[4] = {b4.x, b4.y, b4.z, b4.w};
#pragma unroll
            for (int r = 0; r < 4; ++r)
#pragma unroll
                for (int c = 0; c < 4; ++c)
                    acc[r][c] += a[r] * bb[c];
        }
        __syncthreads();
    }
#pragma unroll
    for (int r = 0; r < 4; ++r) {
        float4 o0 = make_float4(acc[r][0] * scale, acc[r][1] * scale,
                                acc[r][2] * scale, acc[r][3] * scale);
        *(float4*)&Cb[(long)(m0 + ty * 4 + r) * N + n0 + tx * 4] = o0;
    }
}

// ---- weight transposes (Ww -> WwT, Wth -> WthT) -----------------------------
__global__ __launch_bounds__(256) void transpose_g(
    const float* __restrict__ Ww, const float* __restrict__ Wth,
    float* __restrict__ WwT, float* __restrict__ WthT)
{
    __shared__ float tile[32][33];
    int job = blockIdx.z;
    const float* in = job ? Wth : Ww;
    float* outp = job ? WthT : WwT;
    int R  = job ? CI_ : C_;
    int Cc = job ? C_ : CI_;
    int c0 = blockIdx.x * 32, r0 = blockIdx.y * 32;
    if (c0 >= Cc || r0 >= R) return;
    int tx = threadIdx.x & 31, ty = threadIdx.x >> 5;
#pragma unroll
    for (int j = 0; j < 4; ++j)
        tile[ty + 8 * j][tx] = in[(long)(r0 + ty + 8 * j) * Cc + c0 + tx];
    __syncthreads();
#pragma unroll
    for (int j = 0; j < 4; ++j)
        outp[(long)(c0 + ty + 8 * j) * R + r0 + tx] = tile[tx][ty + 8 * j];
}

// ---- rank-1 helpers ---------------------------------------------------------
__global__ __launch_bounds__(256) void rank1_prep(
    const float* __restrict__ Wg, const float* __restrict__ Wph,
    const float* __restrict__ r, float* __restrict__ u1, float* __restrict__ u2)
{
    int b = blockIdx.x, c = threadIdx.x;   // 256
    float s1 = 0.f, s2 = 0.f;
    for (int k = 0; k < C_; ++k) {
        float rv = r[b * C_ + k];
        s1 += Wg[(long)c * C_ + k] * rv;
        s2 += Wph[(long)c * C_ + k] * rv;
    }
    u1[b * CI_ + c] = s1;
    u2[b * CI_ + c] = s2;
}

__global__ __launch_bounds__(256) void rank1_add(
    float* __restrict__ SP, const float* __restrict__ u1, const float* __restrict__ u2,
    const float* __restrict__ bg, const float* __restrict__ bph)
{
    int b = blockIdx.x >> 8, c = blockIdx.x & 255, i = threadIdx.x;
    SP[((long)b * CI_ + c) * CI_ + i] +=
        u1[b * CI_ + c] * bph[i] + bg[c] * (u2[b * CI_ + i] + (float)N_ * bph[i]);
}

// ---- beff -------------------------------------------------------------------
__global__ __launch_bounds__(512) void beff_k(
    const float* __restrict__ P2, const float* __restrict__ bth,
    const float* __restrict__ bw, float* __restrict__ be)
{
    int b = blockIdx.x, o = threadIdx.x;   // 512
    const float* row = P2 + ((long)b * C_ + o) * CI_;
    float s = 0.f;
    for (int i = 0; i < CI_; ++i) s += row[i] * bth[i];
    be[b * C_ + o] = s * (1.0f / (float)N_) + bw[o];
}

// ---- BN finalize + apply ----------------------------------------------------
__global__ __launch_bounds__(512) void bn_finalize(
    const float* __restrict__ sums, const float* __restrict__ ssqs,
    const float* __restrict__ gamma, const float* __restrict__ beta,
    float* __restrict__ sc, float* __restrict__ sh)
{
    int o = threadIdx.x;   // 512
    const float inv = 1.0f / ((float)B_ * (float)N_);
    float mean = sums[o] * inv;
    float var  = ssqs[o] * inv - mean * mean;
    float s = gamma[o] * rsqrtf(var + 1e-5f);
    sc[o] = s;
    sh[o] = beta[o] - mean * s;
}

__global__ __launch_bounds__(256) void bn_apply(
    float* __restrict__ out, const float* __restrict__ v,
    const float* __restrict__ scale, const float* __restrict__ shift)
{
    long i = (long)blockIdx.x * 256 + threadIdx.x;     // float4 index
    int o = (int)((i >> 10) & (C_ - 1));
    float4 wv = ((const float4*)out)[i];
    float4 vv = ((const float4*)v)[i];
    float sc = scale[o], sh = shift[o];
    wv.x = wv.x * sc + sh + vv.x;
    wv.y = wv.y * sc + sh + vv.y;
    wv.z = wv.z * sc + sh + vv.z;
    wv.w = wv.w * sc + sh + vv.w;
    ((float4*)out)[i] = wv;
}

// ---- launch -----------------------------------------------------------------
extern "C" void kernel_launch(void* const* d_in, const int* in_sizes, int n_in,
                              void* d_out, int out_size, void* d_ws, size_t ws_size,
                              hipStream_t stream)
{
    const float* v     = (const float*)d_in[0];
    const float* Wg    = (const float*)d_in[1];
    const float* bg    = (const float*)d_in[2];
    const float* Wth   = (const float*)d_in[3];
    const float* bth   = (const float*)d_in[4];
    const float* Wph   = (const float*)d_in[5];
    const float* bph   = (const float*)d_in[6];
    const float* Ww    = (const float*)d_in[7];
    const float* bw    = (const float*)d_in[8];
    const float* gamma = (const float*)d_in[9];
    const float* beta  = (const float*)d_in[10];
    float* out = (float*)d_out;
    float* ws  = (float*)d_ws;

    float* G    = ws + G_OFF;
    float* P1   = ws + P1_OFF;
    float* SP   = ws + SP_OFF;
    float* P2   = ws + P2_OFF;
    float* Weff = ws + WEFF_OFF;
    float* WwT  = ws + WWT_OFF;
    float* WthT = ws + WTHT_OFF;
    float* r    = ws + R_OFF;
    float* sums = ws + SUM_OFF;
    float* ssqs = ws + SSQ_OFF;
    float* u1   = ws + U1_OFF;
    float* u2   = ws + U2_OFF;
    float* sc   = ws + SC_OFF;
    float* sh   = ws + SH_OFF;
    float* be   = ws + BE_OFF;
    unsigned short* vh  = (unsigned short*)(ws + VH_OFF);
    unsigned short* vl  = (unsigned short*)(ws + VL_OFF);
    unsigned short* vth = (unsigned short*)(ws + VTH_OFF);
    unsigned short* vtl = (unsigned short*)(ws + VTL_OFF);
    unsigned short* weh = (unsigned short*)(ws + WEH_OFF);
    unsigned short* wel = (unsigned short*)(ws + WEL_OFF);
    float* Gp = ws + VTH_OFF;   // gram partials overlay vth/vtl (dead until cast2)

    // zero r + sums + ssqs (contiguous 3072 floats)
    hipMemsetAsync(r, 0, 3072 * sizeof(float), stream);

    // v -> bf16 hi/lo + rowsums
    cast1<<<8192, 256, 0, stream>>>(v, vh, vl, r);

    // G = V V^T  (split-K partials, then reduce)
    gram_mfma<<<dim3(4, 4, 32), 256, 0, stream>>>(vh, vl, Gp);
    reduce_g<<<1024, 256, 0, stream>>>(Gp, G);

    // weight transposes
    transpose_g<<<dim3(16, 16, 2), 256, 0, stream>>>(Ww, Wth, WwT, WthT);

    // P1 = Wg G   [256x512]
    gemm_nt<<<dim3(8, 4, 4), 256, 0, stream>>>(Wg, 0, C_, G, (long)C_ * C_, C_,
                                               P1, (long)CI_ * C_, C_, C_, 1.0f);
    // u1 = Wg r, u2 = Wph r
    rank1_prep<<<4, 256, 0, stream>>>(Wg, Wph, r, u1, u2);
    // S' = P1 Wph^T  [256x256]
    gemm_nt<<<dim3(4, 4, 4), 256, 0, stream>>>(P1, (long)CI_ * C_, C_, Wph, 0, C_,
                                               SP, (long)CI_ * CI_, CI_, C_, 1.0f);
    // S' += u1 bph^T + bg (u2 + N bph)^T
    rank1_add<<<1024, 256, 0, stream>>>(SP, u1, u2, bg, bph);
    // P2 = Ww S'  [512x256]
    gemm_atb64<<<dim3(4, 8, 4), 256, 0, stream>>>(WwT, 0, SP, (long)CI_ * CI_,
                                                  P2, (long)C_ * CI_, C_, CI_, CI_, 1.0f);
    // Weff = (1/N) P2 Wth  [512x512]
    gemm_nt<<<dim3(8, 8, 4), 256, 0, stream>>>(P2, (long)C_ * CI_, CI_, WthT, 0, CI_,
                                               Weff, (long)C_ * C_, C_, CI_, 1.0f / (float)N_);
    // beff
    beff_k<<<4, 512, 0, stream>>>(P2, bth, bw, be);

    // casts for wy
    castW<<<1024, 256, 0, stream>>>(Weff, weh, wel);
    cast2_transpose<<<dim3(128, 16, 4), 256, 0, stream>>>(v, (unsigned int*)vth, (unsigned int*)vtl);

    // Wy + fused BN stats
    wy_mfma<<<dim3(32, 4, 4), 256, 0, stream>>>(weh, wel, vth, vtl, be, out, sums, ssqs);

    // BN finalize + apply (+ residual)
    bn_finalize<<<1, 512, 0, stream>>>(sums, ssqs, gamma, beta, sc, sh);
    bn_apply<<<8192, 256, 0, stream>>>(out, v, sc, sh);
}

// Round 3
// 331.770 us; speedup vs baseline: 1.2637x; 1.1043x over previous
//
#include <hip/hip_runtime.h>
#include <math.h>

// Rs_GCN, round 3: same math as round 2 (proven, absmax 0.03125), launch-count
// 18 -> 12. Fusions: transposes -> NN gemms; rank1_add -> SP epilogue;
// beff -> P2 epilogue; castW -> Weff epilogue; bn_finalize -> bn_apply.
//   G[b] = V V^T (MFMA hi/lo 3-term, split-K=8) -> reduce
//   S'   = Wg G Wph^T + u1 bph^T + bg u2^T + N bg bph^T
//   Weff = (1/N) Ww S' Wth (-> bf16 hi/lo direct) ; beff = Ww S' bth (atomic)
//   Wy   = Weff v + beff/N + bw (MFMA, BN stats fused) -> BN+residual

#define B_  4
#define C_  512
#define CI_ 256
#define N_  4096

typedef __attribute__((ext_vector_type(8))) short bf16x8;
typedef __attribute__((ext_vector_type(4))) float f32x4;

// ---- ws float offsets -------------------------------------------------------
#define G_OFF     0L          // 1,048,576
#define P1_OFF    1048576L    //   524,288
#define SP_OFF    1572864L    //   262,144
#define P2_OFF    1835008L    //   524,288
#define MISC_OFF  2359296L    //     8,192
#define R_OFF     (MISC_OFF + 0)      // 2048
#define SUM_OFF   (MISC_OFF + 2048)   //  512
#define SSQ_OFF   (MISC_OFF + 2560)   //  512
#define BE_OFF    (MISC_OFF + 3072)   // 2048
#define U1_OFF    (MISC_OFF + 5120)   // 1024
#define U2_OFF    (MISC_OFF + 6144)   // 1024
#define VH_OFF    2367488L    // 4,194,304 float slots (ushort x 8,388,608)
#define VL_OFF    6561792L
#define VTH_OFF   10756096L   // Gp (8,388,608 floats) overlays VTH+VTL
#define VTL_OFF   14950400L
#define WEH_OFF   19144704L   //   524,288 slots
#define WEL_OFF   19668992L
// total 20,193,280 floats ~= 81 MB

// ---- helpers ----------------------------------------------------------------
__device__ __forceinline__ unsigned short f2bf(float f) {
    union { float f; unsigned int u; } a; a.f = f;
    unsigned int u = a.u;
    u += 0x7fffu + ((u >> 16) & 1u);      // round-to-nearest-even
    return (unsigned short)(u >> 16);
}
__device__ __forceinline__ float bf2f(unsigned short s) {
    union { unsigned int u; float f; } a; a.u = ((unsigned int)s) << 16; return a.f;
}
__device__ __forceinline__ void gload_lds16(const char* g, char* l) {
    __builtin_amdgcn_global_load_lds(
        (const __attribute__((address_space(1))) unsigned int*)g,
        (__attribute__((address_space(3))) unsigned int*)l, 16, 0, 0);
}

// ---- cast1: v -> vh, vl ; rowsum r (atomics) --------------------------------
__global__ __launch_bounds__(256) void cast1(
    const float* __restrict__ v, unsigned short* __restrict__ vh,
    unsigned short* __restrict__ vl, float* __restrict__ r)
{
    long idx = (long)blockIdx.x * 256 + threadIdx.x;   // float4 index
    float4 f = ((const float4*)v)[idx];
    ushort4 h, l;
    h.x = f2bf(f.x); l.x = f2bf(f.x - bf2f(h.x));
    h.y = f2bf(f.y); l.y = f2bf(f.y - bf2f(h.y));
    h.z = f2bf(f.z); l.z = f2bf(f.z - bf2f(h.z));
    h.w = f2bf(f.w); l.w = f2bf(f.w - bf2f(h.w));
    ((ushort4*)vh)[idx] = h;
    ((ushort4*)vl)[idx] = l;
    float s = f.x + f.y + f.z + f.w;
    s += __shfl_xor(s, 1);  s += __shfl_xor(s, 2);  s += __shfl_xor(s, 4);
    s += __shfl_xor(s, 8);  s += __shfl_xor(s, 16); s += __shfl_xor(s, 32);
    if ((threadIdx.x & 63) == 0) atomicAdd(&r[idx >> 10], s);
}

// ---- cast2: v -> vth, vtl  ([B][N][C], hi/lo packed 2/uint) -----------------
__global__ __launch_bounds__(256) void cast2_transpose(
    const float* __restrict__ v, unsigned int* __restrict__ vth,
    unsigned int* __restrict__ vtl)
{
    __shared__ float tile[32][33];
    const int b = blockIdx.z;
    const int n0 = blockIdx.x * 32, c0 = blockIdx.y * 32;
    const int t = threadIdx.x, tx = t & 31, ty = t >> 5;
#pragma unroll
    for (int j = 0; j < 4; ++j)
        tile[ty + 8 * j][tx] = v[((long)b * C_ + c0 + ty + 8 * j) * N_ + n0 + tx];
    __syncthreads();
#pragma unroll
    for (int p = 0; p < 2; ++p) {
        int nl = p * 16 + (t >> 4);
        int cl = (t & 15) * 2;
        float f0 = tile[cl][nl], f1 = tile[cl + 1][nl];
        unsigned short h0 = f2bf(f0), h1 = f2bf(f1);
        unsigned short l0 = f2bf(f0 - bf2f(h0)), l1 = f2bf(f1 - bf2f(h1));
        long e = ((long)b * N_ + n0 + nl) * C_ + c0 + cl;
        vth[e >> 1] = (unsigned int)h0 | ((unsigned int)h1 << 16);
        vtl[e >> 1] = (unsigned int)l0 | ((unsigned int)l1 << 16);
    }
}

// ---- gram: Gp[z] partial of V V^T (hi/lo 3-term), 128x128 tile, BK=64 -------
__global__ __launch_bounds__(256, 2) void gram_mfma(
    const unsigned short* __restrict__ vh, const unsigned short* __restrict__ vl,
    float* __restrict__ Gp)
{
    __shared__ char smem[65536];    // Ah | Al | Bh | Bl, 16KB each
    const int t = threadIdx.x, lane = t & 63, w = t >> 6;
    const int z = blockIdx.z, b = z >> 3, ch = z & 7;
    const long m0 = blockIdx.y * 128, n0 = blockIdx.x * 128;
    const long k0b = (long)ch * 1024;

    const unsigned short* src = (w & 1) ? vl : vh;
    const long row0 = (w < 2) ? m0 : n0;
    const char* g = (const char*)(src + ((long)b * C_ + row0) * N_) + k0b;
    const long stride = (long)N_ * 2;
    const char* gs = g + (long)(lane >> 3) * stride + (((lane & 7) ^ (lane >> 3)) << 4);
    char* lbase = smem + w * 16384;

    const int wr = w >> 1, wc = w & 1;
    const int l15 = lane & 15, hi4 = lane >> 4;
    const int swz = (l15 & 7) << 4;
    const int arow = (wr * 64 + l15) * 128;
    const int brow = (wc * 64 + l15) * 128;
    const char* Ah = smem;          const char* Al = smem + 16384;
    const char* Bh = smem + 32768;  const char* Bl = smem + 49152;

    f32x4 acc[4][4];
#pragma unroll
    for (int mi = 0; mi < 4; ++mi)
#pragma unroll
        for (int nj = 0; nj < 4; ++nj) acc[mi][nj] = (f32x4){0.f, 0.f, 0.f, 0.f};

    for (int s = 0; s < 8; ++s) {
#pragma unroll
        for (int i = 0; i < 16; ++i)
            gload_lds16(gs + (long)i * 8 * stride + s * 128, lbase + i * 1024);
        __syncthreads();
#pragma unroll
        for (int kk = 0; kk < 2; ++kk) {
            const int off = (kk * 64 + hi4 * 16) ^ swz;
            bf16x8 ah[4], al[4], bh[4], bl[4];
#pragma unroll
            for (int mi = 0; mi < 4; ++mi) {
                ah[mi] = *(const bf16x8*)(Ah + arow + mi * 2048 + off);
                al[mi] = *(const bf16x8*)(Al + arow + mi * 2048 + off);
            }
#pragma unroll
            for (int nj = 0; nj < 4; ++nj) {
                bh[nj] = *(const bf16x8*)(Bh + brow + nj * 2048 + off);
                bl[nj] = *(const bf16x8*)(Bl + brow + nj * 2048 + off);
            }
#pragma unroll
            for (int mi = 0; mi < 4; ++mi)
#pragma unroll
                for (int nj = 0; nj < 4; ++nj) {
                    acc[mi][nj] = __builtin_amdgcn_mfma_f32_16x16x32_bf16(ah[mi], bh[nj], acc[mi][nj], 0, 0, 0);
                    acc[mi][nj] = __builtin_amdgcn_mfma_f32_16x16x32_bf16(ah[mi], bl[nj], acc[mi][nj], 0, 0, 0);
                    acc[mi][nj] = __builtin_amdgcn_mfma_f32_16x16x32_bf16(al[mi], bh[nj], acc[mi][nj], 0, 0, 0);
                }
        }
        __syncthreads();
    }
    float* gp = Gp + (long)z * (C_ * C_);
#pragma unroll
    for (int mi = 0; mi < 4; ++mi)
#pragma unroll
        for (int nj = 0; nj < 4; ++nj)
#pragma unroll
            for (int rr = 0; rr < 4; ++rr) {
                long row = m0 + wr * 64 + mi * 16 + hi4 * 4 + rr;
                long col = n0 + wc * 64 + nj * 16 + l15;
                gp[row * C_ + col] = acc[mi][nj][rr];
            }
}

// ---- reduce gram partials -> G (fp32) ---------------------------------------
__global__ __launch_bounds__(256) void reduce_g(
    const float* __restrict__ Gp, float* __restrict__ G)
{
    long e4 = (long)blockIdx.x * 256 + threadIdx.x;    // float4 idx, 262,144
    long b = e4 >> 16;
    float4 s = make_float4(0.f, 0.f, 0.f, 0.f);
    for (int ch = 0; ch < 8; ++ch) {
        float4 p = ((const float4*)Gp)[(b * 8 + ch) * 65536 + (e4 & 65535)];
        s.x += p.x; s.y += p.y; s.z += p.z; s.w += p.w;
    }
    ((float4*)G)[e4] = s;
}

// ---- wy: out = Weff v + beff/N + bw ; fused BN stats. 128x128, BK=64 --------
__global__ __launch_bounds__(256, 2) void wy_mfma(
    const unsigned short* __restrict__ weh, const unsigned short* __restrict__ wel,
    const unsigned short* __restrict__ vth, const unsigned short* __restrict__ vtl,
    const float* __restrict__ be, const float* __restrict__ bw,
    float* __restrict__ out, float* __restrict__ sums, float* __restrict__ ssqs)
{
    __shared__ char smem[65536];
    const int t = threadIdx.x, lane = t & 63, w = t >> 6;
    const int b = blockIdx.z;
    const long m0 = blockIdx.y * 128;   // o
    const long n0 = blockIdx.x * 128;   // n

    const char* g;
    if (w < 2) g = (const char*)(((w & 1) ? wel : weh) + ((long)b * C_ + m0) * C_);
    else       g = (const char*)(((w & 1) ? vtl : vth) + ((long)b * N_ + n0) * C_);
    const long stride = (long)C_ * 2;
    const char* gs = g + (long)(lane >> 3) * stride + (((lane & 7) ^ (lane >> 3)) << 4);
    char* lbase = smem + w * 16384;

    const int wr = w >> 1, wc = w & 1;
    const int l15 = lane & 15, hi4 = lane >> 4;
    const int swz = (l15 & 7) << 4;
    const int arow = (wr * 64 + l15) * 128;
    const int brow = (wc * 64 + l15) * 128;
    const char* Ah = smem;          const char* Al = smem + 16384;
    const char* Bh = smem + 32768;  const char* Bl = smem + 49152;

    f32x4 acc[4][4];
#pragma unroll
    for (int mi = 0; mi < 4; ++mi)
#pragma unroll
        for (int nj = 0; nj < 4; ++nj) acc[mi][nj] = (f32x4){0.f, 0.f, 0.f, 0.f};

    for (int s = 0; s < 8; ++s) {
#pragma unroll
        for (int i = 0; i < 16; ++i)
            gload_lds16(gs + (long)i * 8 * stride + s * 128, lbase + i * 1024);
        __syncthreads();
#pragma unroll
        for (int kk = 0; kk < 2; ++kk) {
            const int off = (kk * 64 + hi4 * 16) ^ swz;
            bf16x8 ah[4], al[4], bh[4], bl[4];
#pragma unroll
            for (int mi = 0; mi < 4; ++mi) {
                ah[mi] = *(const bf16x8*)(Ah + arow + mi * 2048 + off);
                al[mi] = *(const bf16x8*)(Al + arow + mi * 2048 + off);
            }
#pragma unroll
            for (int nj = 0; nj < 4; ++nj) {
                bh[nj] = *(const bf16x8*)(Bh + brow + nj * 2048 + off);
                bl[nj] = *(const bf16x8*)(Bl + brow + nj * 2048 + off);
            }
#pragma unroll
            for (int mi = 0; mi < 4; ++mi)
#pragma unroll
                for (int nj = 0; nj < 4; ++nj) {
                    acc[mi][nj] = __builtin_amdgcn_mfma_f32_16x16x32_bf16(ah[mi], bh[nj], acc[mi][nj], 0, 0, 0);
                    acc[mi][nj] = __builtin_amdgcn_mfma_f32_16x16x32_bf16(ah[mi], bl[nj], acc[mi][nj], 0, 0, 0);
                    acc[mi][nj] = __builtin_amdgcn_mfma_f32_16x16x32_bf16(al[mi], bh[nj], acc[mi][nj], 0, 0, 0);
                }
        }
        __syncthreads();
    }

    float sm[4][4], sq[4][4];
#pragma unroll
    for (int mi = 0; mi < 4; ++mi)
#pragma unroll
        for (int rr = 0; rr < 4; ++rr) { sm[mi][rr] = 0.f; sq[mi][rr] = 0.f; }

#pragma unroll
    for (int mi = 0; mi < 4; ++mi) {
#pragma unroll
        for (int rr = 0; rr < 4; ++rr) {
            long o = m0 + wr * 64 + mi * 16 + hi4 * 4 + rr;
            float bv = be[b * C_ + o] * (1.0f / (float)N_) + bw[o];
#pragma unroll
            for (int nj = 0; nj < 4; ++nj) {
                long n = n0 + wc * 64 + nj * 16 + l15;
                float val = acc[mi][nj][rr] + bv;
                out[((long)b * C_ + o) * N_ + n] = val;
                sm[mi][rr] += val;
                sq[mi][rr] += val * val;
            }
        }
    }
#pragma unroll
    for (int mi = 0; mi < 4; ++mi)
#pragma unroll
        for (int rr = 0; rr < 4; ++rr) {
            float s1 = sm[mi][rr], s2 = sq[mi][rr];
            s1 += __shfl_xor(s1, 1); s2 += __shfl_xor(s2, 1);
            s1 += __shfl_xor(s1, 2); s2 += __shfl_xor(s2, 2);
            s1 += __shfl_xor(s1, 4); s2 += __shfl_xor(s2, 4);
            s1 += __shfl_xor(s1, 8); s2 += __shfl_xor(s2, 8);
            if (l15 == 0) {
                long o = m0 + wr * 64 + mi * 16 + hi4 * 4 + rr;
                atomicAdd(&sums[o], s1);
                atomicAdd(&ssqs[o], s2);
            }
        }
}

// ---- NN gemm 64x64: C[m][n] = scale * sum_k A[m][k] B[k][n] + epilogues -----
// mode 0: write C. mode 1: write C + beff atomic (bth,be). mode 2: hi/lo cast.
__global__ __launch_bounds__(256) void gemm_nn(
    const float* __restrict__ A, long sA, int lda,
    const float* __restrict__ Bm, long sB, int ldb,
    float* __restrict__ Cm, long sC, int ldc,
    int K, float scale, int mode,
    const float* __restrict__ bth, float* __restrict__ be,
    unsigned short* __restrict__ weh, unsigned short* __restrict__ wel)
{
    int b = blockIdx.z;
    const float* Ab = A + (long)b * sA;
    const float* Bb = Bm + (long)b * sB;
    int i0 = blockIdx.y * 64, j0 = blockIdx.x * 64;

    __shared__ __align__(16) float As[16][64];
    __shared__ __align__(16) float Bs[16][64];

    int t = threadIdx.x, tx = t & 15, ty = t >> 4;
    int am = t >> 2, akq = (t & 3) << 2;
    int bk = t >> 4, bn4 = (t & 15) << 2;

    float acc[4][4];
#pragma unroll
    for (int r = 0; r < 4; ++r)
#pragma unroll
        for (int c = 0; c < 4; ++c) acc[r][c] = 0.f;

    for (int k0 = 0; k0 < K; k0 += 16) {
        float4 va = *(const float4*)&Ab[(long)(i0 + am) * lda + k0 + akq];
        As[akq + 0][am] = va.x; As[akq + 1][am] = va.y;
        As[akq + 2][am] = va.z; As[akq + 3][am] = va.w;
        *(float4*)&Bs[bk][bn4] = *(const float4*)&Bb[(long)(k0 + bk) * ldb + j0 + bn4];
        __syncthreads();
#pragma unroll
        for (int k = 0; k < 16; ++k) {
            float4 a4 = *(float4*)&As[k][ty * 4];
            float4 b4 = *(float4*)&Bs[k][tx * 4];
            float a[4]  = {a4.x, a4.y, a4.z, a4.w};
            float bb[4] = {b4.x, b4.y, b4.z, b4.w};
#pragma unroll
            for (int r = 0; r < 4; ++r)
#pragma unroll
                for (int c = 0; c < 4; ++c)
                    acc[r][c] += a[r] * bb[c];
        }
        __syncthreads();
    }

    if (mode == 2) {   // Weff -> bf16 hi/lo, [b][o=i][p=j]
#pragma unroll
        for (int r = 0; r < 4; ++r) {
            int o = i0 + ty * 4 + r, p = j0 + tx * 4;
            ushort4 h, l;
            float f0 = acc[r][0] * scale, f1 = acc[r][1] * scale;
            float f2 = acc[r][2] * scale, f3 = acc[r][3] * scale;
            h.x = f2bf(f0); l.x = f2bf(f0 - bf2f(h.x));
            h.y = f2bf(f1); l.y = f2bf(f1 - bf2f(h.y));
            h.z = f2bf(f2); l.z = f2bf(f2 - bf2f(h.z));
            h.w = f2bf(f3); l.w = f2bf(f3 - bf2f(h.w));
            long e = (((long)b * C_ + o) * C_ + p) >> 2;
            ((ushort4*)weh)[e] = h;
            ((ushort4*)wel)[e] = l;
        }
        return;
    }
    float* Cb = Cm + (long)b * sC;
#pragma unroll
    for (int r = 0; r < 4; ++r) {
        float4 o0 = make_float4(acc[r][0] * scale, acc[r][1] * scale,
                                acc[r][2] * scale, acc[r][3] * scale);
        *(float4*)&Cb[(long)(i0 + ty * 4 + r) * ldc + j0 + tx * 4] = o0;
    }
    if (mode == 1) {   // beff partial: be[o] += sum_i C[o][i]*bth[i]
#pragma unroll
        for (int r = 0; r < 4; ++r) {
            float pr = acc[r][0] * bth[j0 + tx * 4 + 0]
                     + acc[r][1] * bth[j0 + tx * 4 + 1]
                     + acc[r][2] * bth[j0 + tx * 4 + 2]
                     + acc[r][3] * bth[j0 + tx * 4 + 3];
            pr += __shfl_xor(pr, 1); pr += __shfl_xor(pr, 2);
            pr += __shfl_xor(pr, 4); pr += __shfl_xor(pr, 8);
            if (tx == 0) atomicAdd(&be[b * C_ + i0 + ty * 4 + r], pr);
        }
    }
}

// ---- SP (NT) = P1 Wph^T + rank-1 epilogue -----------------------------------
__global__ __launch_bounds__(256) void gemm_nt_sp(
    const float* __restrict__ P1, const float* __restrict__ Wph,
    float* __restrict__ SP, const float* __restrict__ u1,
    const float* __restrict__ u2, const float* __restrict__ bg,
    const float* __restrict__ bph)
{
    int b = blockIdx.z;
    const float* Ab = P1 + (long)b * (CI_ * C_);
    int i0 = blockIdx.y * 64, j0 = blockIdx.x * 64;

    __shared__ __align__(16) float As[16][64];
    __shared__ __align__(16) float Bs[16][64];

    int t = threadIdx.x, tx = t & 15, ty = t >> 4;
    int lr = t >> 2, lk = (t & 3) << 2;

    float acc[4][4];
#pragma unroll
    for (int r = 0; r < 4; ++r)
#pragma unroll
        for (int c = 0; c < 4; ++c) acc[r][c] = 0.f;

    for (int kt = 0; kt < C_; kt += 16) {
        float4 va = *(const float4*)&Ab[(long)(i0 + lr) * C_ + kt + lk];
        float4 vb = *(const float4*)&Wph[(long)(j0 + lr) * C_ + kt + lk];
        As[lk + 0][lr] = va.x; As[lk + 1][lr] = va.y; As[lk + 2][lr] = va.z; As[lk + 3][lr] = va.w;
        Bs[lk + 0][lr] = vb.x; Bs[lk + 1][lr] = vb.y; Bs[lk + 2][lr] = vb.z; Bs[lk + 3][lr] = vb.w;
        __syncthreads();
#pragma unroll
        for (int k = 0; k < 16; ++k) {
            float4 a4 = *(float4*)&As[k][ty * 4];
            float4 b4 = *(float4*)&Bs[k][tx * 4];
            float a[4]  = {a4.x, a4.y, a4.z, a4.w};
            float bb[4] = {b4.x, b4.y, b4.z, b4.w};
#pragma unroll
            for (int r = 0; r < 4; ++r)
#pragma unroll
                for (int c = 0; c < 4; ++c)
                    acc[r][c] += a[r] * bb[c];
        }
        __syncthreads();
    }
    float* Cb = SP + (long)b * (CI_ * CI_);
#pragma unroll
    for (int r = 0; r < 4; ++r) {
        int cr = i0 + ty * 4 + r;
        float u1v = u1[b * CI_ + cr], bgv = bg[cr];
        float4 o0;
        float* po = (float*)&o0;
#pragma unroll
        for (int c = 0; c < 4; ++c) {
            int ic = j0 + tx * 4 + c;
            po[c] = acc[r][c] + u1v * bph[ic] + bgv * (u2[b * CI_ + ic] + (float)N_ * bph[ic]);
        }
        *(float4*)&Cb[(long)cr * CI_ + j0 + tx * 4] = o0;
    }
}

// ---- rank1_prep: u1 = Wg r, u2 = Wph r (16 blocks) --------------------------
__global__ __launch_bounds__(256) void rank1_prep(
    const float* __restrict__ Wg, const float* __restrict__ Wph,
    const float* __restrict__ r, float* __restrict__ u1, float* __restrict__ u2)
{
    int blk = blockIdx.x;                 // 16 = 4 b x 4 quarters
    int b = blk >> 2, q = blk & 3;
    int t = threadIdx.x;
    int c = q * 64 + (t >> 2);            // Ci index
    int kq = t & 3;                       // k-quarter (128 each)
    const float* rb = r + b * C_;
    float s1 = 0.f, s2 = 0.f;
    for (int k = kq * 128; k < kq * 128 + 128; k += 4) {
        float4 wg = *(const float4*)&Wg[(long)c * C_ + k];
        float4 wp = *(const float4*)&Wph[(long)c * C_ + k];
        float4 rv = *(const float4*)&rb[k];
        s1 += wg.x * rv.x + wg.y * rv.y + wg.z * rv.z + wg.w * rv.w;
        s2 += wp.x * rv.x + wp.y * rv.y + wp.z * rv.z + wp.w * rv.w;
    }
    s1 += __shfl_xor(s1, 1); s2 += __shfl_xor(s2, 1);
    s1 += __shfl_xor(s1, 2); s2 += __shfl_xor(s2, 2);
    if (kq == 0) {
        u1[b * CI_ + c] = s1;
        u2[b * CI_ + c] = s2;
    }
}

// ---- bn_apply with inline finalize: out = out*sc + sh + v -------------------
__global__ __launch_bounds__(256) void bn_apply(
    float* __restrict__ out, const float* __restrict__ v,
    const float* __restrict__ sums, const float* __restrict__ ssqs,
    const float* __restrict__ gamma, const float* __restrict__ beta)
{
    long i = (long)blockIdx.x * 256 + threadIdx.x;     // float4 index
    int o = (int)((i >> 10) & (C_ - 1));
    const float inv = 1.0f / ((float)B_ * (float)N_);
    float mean = sums[o] * inv;
    float var  = ssqs[o] * inv - mean * mean;
    float sc = gamma[o] * rsqrtf(var + 1e-5f);
    float sh = beta[o] - mean * sc;
    float4 wv = ((const float4*)out)[i];
    float4 vv = ((const float4*)v)[i];
    wv.x = wv.x * sc + sh + vv.x;
    wv.y = wv.y * sc + sh + vv.y;
    wv.z = wv.z * sc + sh + vv.z;
    wv.w = wv.w * sc + sh + vv.w;
    ((float4*)out)[i] = wv;
}

// ---- launch -----------------------------------------------------------------
extern "C" void kernel_launch(void* const* d_in, const int* in_sizes, int n_in,
                              void* d_out, int out_size, void* d_ws, size_t ws_size,
                              hipStream_t stream)
{
    const float* v     = (const float*)d_in[0];
    const float* Wg    = (const float*)d_in[1];
    const float* bg    = (const float*)d_in[2];
    const float* Wth   = (const float*)d_in[3];
    const float* bth   = (const float*)d_in[4];
    const float* Wph   = (const float*)d_in[5];
    const float* bph   = (const float*)d_in[6];
    const float* Ww    = (const float*)d_in[7];
    const float* bw    = (const float*)d_in[8];
    const float* gamma = (const float*)d_in[9];
    const float* beta  = (const float*)d_in[10];
    float* out = (float*)d_out;
    float* ws  = (float*)d_ws;

    float* G    = ws + G_OFF;
    float* P1   = ws + P1_OFF;
    float* SP   = ws + SP_OFF;
    float* P2   = ws + P2_OFF;
    float* r    = ws + R_OFF;
    float* sums = ws + SUM_OFF;
    float* ssqs = ws + SSQ_OFF;
    float* be   = ws + BE_OFF;
    float* u1   = ws + U1_OFF;
    float* u2   = ws + U2_OFF;
    unsigned short* vh  = (unsigned short*)(ws + VH_OFF);
    unsigned short* vl  = (unsigned short*)(ws + VL_OFF);
    unsigned short* vth = (unsigned short*)(ws + VTH_OFF);
    unsigned short* vtl = (unsigned short*)(ws + VTL_OFF);
    unsigned short* weh = (unsigned short*)(ws + WEH_OFF);
    unsigned short* wel = (unsigned short*)(ws + WEL_OFF);
    float* Gp = ws + VTH_OFF;   // gram partials overlay vth/vtl (dead until cast2)

    // zero r + sums + ssqs + be (contiguous 5120 floats)
    hipMemsetAsync(r, 0, 5120 * sizeof(float), stream);

    // v -> bf16 hi/lo + rowsums
    cast1<<<8192, 256, 0, stream>>>(v, vh, vl, r);

    // G = V V^T
    gram_mfma<<<dim3(4, 4, 32), 256, 0, stream>>>(vh, vl, Gp);
    reduce_g<<<1024, 256, 0, stream>>>(Gp, G);

    // v -> [B][N][C] hi/lo (after Gp is consumed; overlays it)
    cast2_transpose<<<dim3(128, 16, 4), 256, 0, stream>>>(v, (unsigned int*)vth, (unsigned int*)vtl);

    // u1 = Wg r, u2 = Wph r
    rank1_prep<<<16, 256, 0, stream>>>(Wg, Wph, r, u1, u2);

    // P1 = Wg G   [256x512]
    gemm_nn<<<dim3(8, 4, 4), 256, 0, stream>>>(
        Wg, 0, C_, G, (long)C_ * C_, C_, P1, (long)CI_ * C_, C_,
        C_, 1.0f, 0, nullptr, nullptr, nullptr, nullptr);

    // S' = P1 Wph^T + rank-1   [256x256]
    gemm_nt_sp<<<dim3(4, 4, 4), 256, 0, stream>>>(P1, Wph, SP, u1, u2, bg, bph);

    // P2 = Ww S'  [512x256]  + beff atomics
    gemm_nn<<<dim3(4, 8, 4), 256, 0, stream>>>(
        Ww, 0, CI_, SP, (long)CI_ * CI_, CI_, P2, (long)C_ * CI_, CI_,
        CI_, 1.0f, 1, bth, be, nullptr, nullptr);

    // Weff = (1/N) P2 Wth -> bf16 hi/lo  [512x512]
    gemm_nn<<<dim3(8, 8, 4), 256, 0, stream>>>(
        P2, (long)C_ * CI_, CI_, Wth, 0, C_, nullptr, 0, 0,
        CI_, 1.0f / (float)N_, 2, nullptr, nullptr, weh, wel);

    // Wy + fused BN stats
    wy_mfma<<<dim3(32, 4, 4), 256, 0, stream>>>(weh, wel, vth, vtl, be, bw, out, sums, ssqs);

    // BN finalize+apply (+ residual)
    bn_apply<<<8192, 256, 0, stream>>>(out, v, sums, ssqs, gamma, beta);
}